// Round 2
// baseline (333.674 us; speedup 1.0000x reference)
//
#include <hip/hip_runtime.h>
#include <hip/hip_cooperative_groups.h>
#include <math.h>

namespace cg = cooperative_groups;

#define B_ 32
#define C_ 128
#define L_ 4096
#define G_ 8
#define ROWS (B_ * C_)                 // 4096 rows of 4096 floats
#define CHUNKS ((B_ * C_ * L_) / 1024) // 16384 chunks of 1024 elements

typedef float fx4 __attribute__((ext_vector_type(4)));

// ---------------- shared prep body (works for 128- or 256-thread blocks) ----------------
__device__ __forceinline__ void prep_body(const int tid,
                                          const float* __restrict__ pmin,
                                          const float* __restrict__ pmax,
                                          const float* __restrict__ alpha,
                                          float* __restrict__ wq,    // [G_][C_]
                                          float* __restrict__ offv,  // [C_]
                                          float* __restrict__ scv,   // [G_]
                                          float* __restrict__ zpv) { // [G_]
    __shared__ float smin[C_], smax[C_];
    __shared__ int markN[C_], markX[C_];
    __shared__ float gmin[G_], gmax[G_];
    __shared__ float ssc[G_], szp[G_];
    const int c = tid;
    if (c < C_) {
        float a = INFINITY, b = -INFINITY;
        for (int j = 0; j < B_; ++j) {
            a = fminf(a, pmin[c * B_ + j]);
            b = fmaxf(b, pmax[c * B_ + j]);
        }
        smin[c] = fminf(a, -4.0f);   // ch_min = min(.., INIT_MIN)
        smax[c] = fmaxf(b, 6.0f);    // ch_max = max(.., INIT_MAX)
    }
    __syncthreads();
    // range of each 128-vector (every thread recomputes; broadcast-friendly)
    float rminN = INFINITY, rmaxN = -INFINITY, rminX = INFINITY, rmaxX = -INFINITY;
    for (int j = 0; j < C_; ++j) {
        float u = smin[j], v = smax[j];
        rminN = fminf(rminN, u); rmaxN = fmaxf(rmaxN, u);
        rminX = fminf(rminX, v); rmaxX = fmaxf(rmaxX, v);
    }
    const float divN = rmaxN - rminN, divX = rmaxX - rminX;
    float bN[G_ + 1], bX[G_ + 1];
#pragma unroll
    for (int m = 0; m <= G_; ++m) {
        // replicate: rmin + div * (m/8) in f32, exact order
        bN[m] = rminN + __fmul_rn(divN, (float)m * 0.125f);
        bX[m] = rminX + __fmul_rn(divX, (float)m * 0.125f);
    }
    if (c < C_) {
        int mN = 0, mX = 0;
        const float vN = smin[c], vX = smax[c];
#pragma unroll
        for (int m = 0; m < G_; ++m) {  // ascending: later bins win shared edges
            if (vN >= bN[m] && vN <= bN[m + 1]) mN = m + 1;
            if (vX >= bX[m] && vX <= bX[m + 1]) mX = m + 1;
        }
        markN[c] = mN; markX[c] = mX;
    }
    __syncthreads();
    if (c < G_) {               // 'min' stats for ch_min
        float s = INFINITY; bool found = false;
        for (int j = 0; j < C_; ++j)
            if (markN[j] == c + 1) { s = fminf(s, smin[j]); found = true; }
        gmin[c] = found ? s : bN[c + 1];
    } else if (c < 2 * G_) {    // 'max' stats for ch_max
        const int g = c - G_;
        float s = -INFINITY; bool found = false;
        for (int j = 0; j < C_; ++j)
            if (markX[j] == g + 1) { s = fmaxf(s, smax[j]); found = true; }
        gmax[g] = found ? s : bX[g + 1];
    }
    __syncthreads();
    if (c < G_) {
        const float left = gmin[c], right = gmax[c];
        const float sc = 255.0f / fmaxf(right - left, 1e-8f);
        const float zp = rintf(__fmul_rn(sc, left)) + 128.0f;
        ssc[c] = sc; szp[c] = zp;
        scv[c] = sc; zpv[c] = zp;
    }
    __syncthreads();
    if (c < C_) {
        float av[G_];
        float amax = -INFINITY;
#pragma unroll
        for (int g = 0; g < G_; ++g) { av[g] = alpha[g * C_ + c]; amax = fmaxf(amax, av[g]); }
        float sum = 0.0f;
#pragma unroll
        for (int g = 0; g < G_; ++g) { av[g] = expf(av[g] - amax); sum += av[g]; }
        float offc = 0.0f;
#pragma unroll
        for (int g = 0; g < G_; ++g) {
            float w = (av[g] / sum) / ssc[g];   // w = softmax/scale
            wq[g * C_ + c] = w;
            offc += w * szp[g];                 // off = sum w*zp
        }
        offv[c] = offc;
    }
}

// ---------------- fused cooperative kernel ----------------
__global__ __launch_bounds__(256, 4) void fused(const float* __restrict__ x,
                                                const float* __restrict__ alpha,
                                                float* __restrict__ out,
                                                float* __restrict__ ws) {
    const int tid = threadIdx.x;
    const int bid = blockIdx.x;
    const int nblk = gridDim.x;
    float* pmin = ws;              // [C_*B_]
    float* pmax = ws + 4096;
    float* wq   = ws + 8192;       // [G_*C_]
    float* offv = ws + 9216;       // [C_]
    float* scv  = ws + 9344;       // [G_]
    float* zpv  = ws + 9352;       // [G_]

    // ---- Phase A: per-(b,c) row min/max partials (also warms x into L3) ----
    {
        __shared__ float rs0[4], rs1[4];
        const int wave = tid >> 6, lane = tid & 63;
        for (int r = bid; r < ROWS; r += nblk) {
            const fx4* xv = (const fx4*)(x + (size_t)r * L_);
            float vmin = INFINITY, vmax = -INFINITY;
#pragma unroll
            for (int i = 0; i < 4; ++i) {
                fx4 v = xv[i * 256 + tid];
                vmin = fminf(vmin, fminf(fminf(v[0], v[1]), fminf(v[2], v[3])));
                vmax = fmaxf(vmax, fmaxf(fmaxf(v[0], v[1]), fmaxf(v[2], v[3])));
            }
#pragma unroll
            for (int off = 32; off > 0; off >>= 1) {
                vmin = fminf(vmin, __shfl_down(vmin, off, 64));
                vmax = fmaxf(vmax, __shfl_down(vmax, off, 64));
            }
            if (lane == 0) { rs0[wave] = vmin; rs1[wave] = vmax; }
            __syncthreads();
            if (tid == 0) {
                float m0 = fminf(fminf(rs0[0], rs0[1]), fminf(rs0[2], rs0[3]));
                float m1 = fmaxf(fmaxf(rs1[0], rs1[1]), fmaxf(rs1[2], rs1[3]));
                const int b = r >> 7, c = r & (C_ - 1);
                pmin[c * B_ + b] = m0;
                pmax[c * B_ + b] = m1;
            }
            __syncthreads();
        }
    }
    __threadfence();
    cg::this_grid().sync();

    // ---- Phase B: group quantization + softmax + folded coefficients ----
    if (bid == 0) prep_body(tid, pmin, pmax, alpha, wq, offv, scv, zpv);
    __threadfence();
    cg::this_grid().sync();

    // ---- Phase C: elementwise apply (x read should L3-hit; nt store for out) ----
    float s[G_], z[G_];
#pragma unroll
    for (int g = 0; g < G_; ++g) { s[g] = scv[g]; z[g] = zpv[g]; }
    for (int ch = bid; ch < CHUNKS; ch += nblk) {
        const int c = (ch >> 2) & (C_ - 1);   // 4 chunks per (b,c) row
        float w[G_];
#pragma unroll
        for (int g = 0; g < G_; ++g) w[g] = wq[g * C_ + c];
        const float offc = offv[c];
        const size_t idx = (size_t)ch * 256 + tid;
        fx4 xv = ((const fx4*)x)[idx];
        fx4 rv;
#pragma unroll
        for (int i = 0; i < 4; ++i) {
            float acc = offc;
#pragma unroll
            for (int g = 0; g < G_; ++g) {
                float t = __fmul_rn(s[g], xv[i]) - z[g];  // no fma contraction
                float q = rintf(t);                       // round half-to-even
                q = fminf(fmaxf(q, -128.0f), 127.0f);     // clamp(q,-n,n-1)
                acc = fmaf(w[g], q, acc);
            }
            rv[i] = acc;
        }
        __builtin_nontemporal_store(rv, (fx4*)out + idx);
    }
}

// ---------------- fallback (non-cooperative) path ----------------
__global__ __launch_bounds__(256) void k_minmax(const float* __restrict__ x,
                                                float* __restrict__ pmin,
                                                float* __restrict__ pmax) {
    const int p = blockIdx.x;
    const int tid = threadIdx.x;
    const fx4* xv = (const fx4*)(x + (size_t)p * L_);
    float vmin = INFINITY, vmax = -INFINITY;
#pragma unroll
    for (int i = 0; i < 4; ++i) {
        fx4 v = xv[i * 256 + tid];
        vmin = fminf(vmin, fminf(fminf(v[0], v[1]), fminf(v[2], v[3])));
        vmax = fmaxf(vmax, fmaxf(fmaxf(v[0], v[1]), fmaxf(v[2], v[3])));
    }
#pragma unroll
    for (int off = 32; off > 0; off >>= 1) {
        vmin = fminf(vmin, __shfl_down(vmin, off, 64));
        vmax = fmaxf(vmax, __shfl_down(vmax, off, 64));
    }
    __shared__ float smin[4], smax[4];
    const int wave = tid >> 6, lane = tid & 63;
    if (lane == 0) { smin[wave] = vmin; smax[wave] = vmax; }
    __syncthreads();
    if (tid == 0) {
        float m0 = fminf(fminf(smin[0], smin[1]), fminf(smin[2], smin[3]));
        float m1 = fmaxf(fmaxf(smax[0], smax[1]), fmaxf(smax[2], smax[3]));
        int b = p >> 7, c = p & (C_ - 1);
        pmin[c * B_ + b] = m0;
        pmax[c * B_ + b] = m1;
    }
}

__global__ __launch_bounds__(128) void k_prep(const float* __restrict__ pmin,
                                              const float* __restrict__ pmax,
                                              const float* __restrict__ alpha,
                                              float* __restrict__ wq,
                                              float* __restrict__ offv,
                                              float* __restrict__ scv,
                                              float* __restrict__ zpv) {
    prep_body(threadIdx.x, pmin, pmax, alpha, wq, offv, scv, zpv);
}

__global__ __launch_bounds__(256) void k_apply(const float* __restrict__ x,
                                               const float* __restrict__ wq,
                                               const float* __restrict__ offv,
                                               const float* __restrict__ scv,
                                               const float* __restrict__ zpv,
                                               float* __restrict__ out) {
    const int c = (blockIdx.x >> 2) & (C_ - 1);
    float s[G_], z[G_], w[G_];
#pragma unroll
    for (int g = 0; g < G_; ++g) { s[g] = scv[g]; z[g] = zpv[g]; w[g] = wq[g * C_ + c]; }
    const float offc = offv[c];
    const size_t idx = (size_t)blockIdx.x * 256 + threadIdx.x;
    fx4 xv = ((const fx4*)x)[idx];
    fx4 rv;
#pragma unroll
    for (int i = 0; i < 4; ++i) {
        float acc = offc;
#pragma unroll
        for (int g = 0; g < G_; ++g) {
            float t = __fmul_rn(s[g], xv[i]) - z[g];
            float q = rintf(t);
            q = fminf(fmaxf(q, -128.0f), 127.0f);
            acc = fmaf(w[g], q, acc);
        }
        rv[i] = acc;
    }
    __builtin_nontemporal_store(rv, (fx4*)out + idx);
}

extern "C" void kernel_launch(void* const* d_in, const int* in_sizes, int n_in,
                              void* d_out, int out_size, void* d_ws, size_t ws_size,
                              hipStream_t stream) {
    const float* x = (const float*)d_in[0];       // [32,128,4096]
    const float* alpha = (const float*)d_in[1];   // [8,128]
    float* out = (float*)d_out;
    float* ws = (float*)d_ws;

    float* pmin = ws;
    float* pmax = ws + 4096;
    float* wq   = ws + 8192;
    float* offv = ws + 9216;
    float* scv  = ws + 9344;
    float* zpv  = ws + 9352;

    // grid sized to guaranteed co-residency (cooperative requirement)
    int per_cu = 0;
    hipError_t oe = hipOccupancyMaxActiveBlocksPerMultiprocessor(&per_cu, fused, 256, 0);
    int nblk = (oe == hipSuccess ? per_cu : 0) * 256;   // 256 CUs on MI355X
    if (nblk > 2048) nblk = 2048;

    hipError_t le = hipErrorUnknown;
    if (nblk >= 64) {
        void* args[] = {(void*)&x, (void*)&alpha, (void*)&out, (void*)&ws};
        le = hipLaunchCooperativeKernel((const void*)fused, dim3(nblk), dim3(256),
                                        args, 0, stream);
    }
    if (le != hipSuccess) {
        // non-cooperative fallback (3 dispatches)
        k_minmax<<<ROWS, 256, 0, stream>>>(x, pmin, pmax);
        k_prep<<<1, 128, 0, stream>>>(pmin, pmax, alpha, wq, offv, scv, zpv);
        k_apply<<<CHUNKS, 256, 0, stream>>>(x, wq, offv, scv, zpv, out);
    }
}

// Round 3
// 62.214 us; speedup vs baseline: 5.3633x; 5.3633x over previous
//
#include <hip/hip_runtime.h>
#include <math.h>

#define B_ 32
#define C_ 128
#define L_ 4096
#define G_ 8
#define ROWS (B_ * C_)   // 4096 rows of 4096 floats

typedef float fx4 __attribute__((ext_vector_type(4)));

// ---------------- Kernel 1: per-(b,c) row min/max, one wave per row ----------------
// 1024 blocks x 256 threads = 4096 waves; wave w of block bid handles row 4*bid+w.
// 16 float4 loads per lane (256 B), shuffle-only reduction, no __syncthreads.
__global__ __launch_bounds__(256) void k_minmax(const float* __restrict__ x,
                                                float* __restrict__ pmin,
                                                float* __restrict__ pmax) {
    const int tid = threadIdx.x;
    const int wave = tid >> 6, lane = tid & 63;
    const int r = blockIdx.x * 4 + wave;          // row index, 0..4095
    const fx4* xv = (const fx4*)x + (size_t)r * (L_ / 4);
    float vmin = INFINITY, vmax = -INFINITY;
#pragma unroll
    for (int i = 0; i < 16; ++i) {
        fx4 v = xv[i * 64 + lane];
        vmin = fminf(vmin, fminf(fminf(v[0], v[1]), fminf(v[2], v[3])));
        vmax = fmaxf(vmax, fmaxf(fmaxf(v[0], v[1]), fmaxf(v[2], v[3])));
    }
#pragma unroll
    for (int off = 32; off > 0; off >>= 1) {
        vmin = fminf(vmin, __shfl_down(vmin, off, 64));
        vmax = fmaxf(vmax, __shfl_down(vmax, off, 64));
    }
    if (lane == 0) {
        const int b = r >> 7, c = r & (C_ - 1);
        pmin[c * B_ + b] = vmin;
        pmax[c * B_ + b] = vmax;
    }
}

// ---------------- Kernel 2: group binning + softmax + folded coefficients ----------------
// 1 block of 128 threads (thread = channel).
__global__ __launch_bounds__(128) void k_prep(const float* __restrict__ pmin,
                                              const float* __restrict__ pmax,
                                              const float* __restrict__ alpha,
                                              float* __restrict__ wq,    // [G_][C_]
                                              float* __restrict__ offv,  // [C_]
                                              float* __restrict__ scv,   // [G_]
                                              float* __restrict__ zpv) { // [G_]
    const int c = threadIdx.x; // 0..127
    __shared__ float smin[C_], smax[C_];
    __shared__ int markN[C_], markX[C_];
    __shared__ float gmin[G_], gmax[G_];
    __shared__ float ssc[G_], szp[G_];

    // reduce the 32 per-batch partials for this channel (vectorized) + INIT clamps
    {
        const fx4* pn = (const fx4*)pmin + c * (B_ / 4);
        const fx4* px = (const fx4*)pmax + c * (B_ / 4);
        float a = INFINITY, b = -INFINITY;
#pragma unroll
        for (int i = 0; i < B_ / 4; ++i) {
            fx4 u = pn[i], v = px[i];
            a = fminf(a, fminf(fminf(u[0], u[1]), fminf(u[2], u[3])));
            b = fmaxf(b, fmaxf(fmaxf(v[0], v[1]), fmaxf(v[2], v[3])));
        }
        smin[c] = fminf(a, -4.0f);   // ch_min = min(.., INIT_MIN)
        smax[c] = fmaxf(b, 6.0f);    // ch_max = max(.., INIT_MAX)
    }
    __syncthreads();

    // range of each 128-vector (every thread recomputes; broadcast reads)
    float rminN = INFINITY, rmaxN = -INFINITY, rminX = INFINITY, rmaxX = -INFINITY;
    for (int j = 0; j < C_; ++j) {
        float u = smin[j], v = smax[j];
        rminN = fminf(rminN, u); rmaxN = fmaxf(rmaxN, u);
        rminX = fminf(rminX, v); rmaxX = fmaxf(rmaxX, v);
    }
    const float divN = rmaxN - rminN, divX = rmaxX - rminX;
    float bN[G_ + 1], bX[G_ + 1];
#pragma unroll
    for (int m = 0; m <= G_; ++m) {
        // replicate: rmin + div * (m/8) in f32, exact order
        bN[m] = rminN + __fmul_rn(divN, (float)m * 0.125f);
        bX[m] = rminX + __fmul_rn(divX, (float)m * 0.125f);
    }
    // mark: ascending m, later bins overwrite at shared edges
    {
        int mN = 0, mX = 0;
        const float vN = smin[c], vX = smax[c];
#pragma unroll
        for (int m = 0; m < G_; ++m) {
            if (vN >= bN[m] && vN <= bN[m + 1]) mN = m + 1;
            if (vX >= bX[m] && vX <= bX[m + 1]) mX = m + 1;
        }
        markN[c] = mN; markX[c] = mX;
    }
    __syncthreads();

    if (c < G_) {               // 'min' stats over ch_min bins
        float s = INFINITY; bool found = false;
        for (int j = 0; j < C_; ++j)
            if (markN[j] == c + 1) { s = fminf(s, smin[j]); found = true; }
        gmin[c] = found ? s : bN[c + 1];
    } else if (c < 2 * G_) {    // 'max' stats over ch_max bins
        const int g = c - G_;
        float s = -INFINITY; bool found = false;
        for (int j = 0; j < C_; ++j)
            if (markX[j] == g + 1) { s = fmaxf(s, smax[j]); found = true; }
        gmax[g] = found ? s : bX[g + 1];
    }
    __syncthreads();

    if (c < G_) {
        const float left = gmin[c], right = gmax[c];
        const float sc = 255.0f / fmaxf(right - left, 1e-8f);
        const float zp = rintf(__fmul_rn(sc, left)) + 128.0f;
        ssc[c] = sc; szp[c] = zp;
        scv[c] = sc; zpv[c] = zp;
    }
    __syncthreads();

    // softmax over G for channel c; fold: w = sw/scale, off = sum w*zp
    float av[G_];
    float amax = -INFINITY;
#pragma unroll
    for (int g = 0; g < G_; ++g) { av[g] = alpha[g * C_ + c]; amax = fmaxf(amax, av[g]); }
    float sum = 0.0f;
#pragma unroll
    for (int g = 0; g < G_; ++g) { av[g] = expf(av[g] - amax); sum += av[g]; }
    float offc = 0.0f;
#pragma unroll
    for (int g = 0; g < G_; ++g) {
        float w = (av[g] / sum) / ssc[g];
        wq[g * C_ + c] = w;
        offc += w * szp[g];
    }
    offv[c] = offc;
}

// ---------------- Kernel 3: elementwise apply, one block per row ----------------
// out[idx] = off[c] + sum_g w[g,c] * clamp(rint(s_g*x - zp_g), -128, 127)
// 4096 blocks x 256 threads; thread handles 4 float4 of its row (cached stores:
// out lingers dirty in L2/L3, writeback off the critical path; x reads L3-hit).
__global__ __launch_bounds__(256) void k_apply(const float* __restrict__ x,
                                               const float* __restrict__ wq,
                                               const float* __restrict__ offv,
                                               const float* __restrict__ scv,
                                               const float* __restrict__ zpv,
                                               float* __restrict__ out) {
    const int c = blockIdx.x & (C_ - 1);          // row = b*C_ + c
    float s[G_], z[G_], w[G_];
#pragma unroll
    for (int g = 0; g < G_; ++g) {
        s[g] = scv[g];
        z[g] = zpv[g];
        w[g] = wq[g * C_ + c];
    }
    const float offc = offv[c];
    const size_t base = (size_t)blockIdx.x * (L_ / 4) + threadIdx.x;
#pragma unroll
    for (int i = 0; i < 4; ++i) {
        const size_t idx = base + i * 256;
        fx4 xv = ((const fx4*)x)[idx];
        fx4 rv;
#pragma unroll
        for (int k = 0; k < 4; ++k) {
            float acc = offc;
#pragma unroll
            for (int g = 0; g < G_; ++g) {
                float t = __fmul_rn(s[g], xv[k]) - z[g];  // no fma contraction
                float q = rintf(t);                       // round half-to-even
                q = fminf(fmaxf(q, -128.0f), 127.0f);     // clamp(q,-n,n-1)
                acc = fmaf(w[g], q, acc);
            }
            rv[k] = acc;
        }
        ((fx4*)out)[idx] = rv;
    }
}

extern "C" void kernel_launch(void* const* d_in, const int* in_sizes, int n_in,
                              void* d_out, int out_size, void* d_ws, size_t ws_size,
                              hipStream_t stream) {
    const float* x = (const float*)d_in[0];       // [32,128,4096]
    const float* alpha = (const float*)d_in[1];   // [8,128]
    float* out = (float*)d_out;
    float* ws = (float*)d_ws;

    float* pmin = ws;              // [C_*B_] = 4096
    float* pmax = ws + 4096;       // 4096
    float* wq   = ws + 8192;       // [G_*C_] = 1024
    float* offv = ws + 9216;       // 128
    float* scv  = ws + 9344;       // 8
    float* zpv  = ws + 9352;       // 8

    k_minmax<<<ROWS / 4, 256, 0, stream>>>(x, pmin, pmax);
    k_prep<<<1, 128, 0, stream>>>(pmin, pmax, alpha, wq, offv, scv, zpv);
    k_apply<<<ROWS, 256, 0, stream>>>(x, wq, offv, scv, zpv, out);
}